// Round 2
// baseline (90.957 us; speedup 1.0000x reference)
//
#include <hip/hip_runtime.h>

// permittivity = sigmoid((Z - 0.5)/T), Z = sum of 96 isotropic Gaussians on a
// 4001x4001 grid over [-10,10]^2.
//
// Exact-reduction strategy:
//  1. Per-block hole culling vs tile rect: exponent >= 34 -> contribution
//     < e^-34 ~ 2e-15, invisible vs 2e-2 threshold.
//  2. Separable exp: exp(-(dx^2+dy^2)/2s^2) = ex(dx)*ey(dy): 10 exp2 + 16 FMA
//     per hole per 16-pixel thread tile.
//  3. Block-uniform fast path for empty shortlists (~84% of tiles): store a
//     single precomputed sigmoid(-0.5/T) constant, no transcendentals.
// Regime: write-BW-bound on the 64 MB output (floor ~11 us at 6 TB/s).

#define NGRID 4001
#define TI 32      // rows (x-axis) per block
#define TJ 128     // cols (y-axis) per block
#define MAXH 128   // LDS shortlist capacity (only 96 holes exist)

__global__ __launch_bounds__(256) void permit_kernel(
    const float* __restrict__ holes, int nh,
    const float* __restrict__ Tptr,
    float* __restrict__ out)
{
    __shared__ float4 sh[MAXH];
    __shared__ int scnt;

    const float step    = 20.0f / 4000.0f;
    const float x_start = -10.0f;
    const float LOG2E   = 1.4426950408889634f;

    const int i0 = blockIdx.y * TI;  // row (x) origin
    const int j0 = blockIdx.x * TJ;  // col (y) origin

    // Tile rect bounds (block-uniform) for culling.
    const float txlo = x_start + i0 * step;
    const float txhi = x_start + (float)min(i0 + TI - 1, NGRID - 1) * step;
    const float tylo = x_start + j0 * step;
    const float tyhi = x_start + (float)min(j0 + TJ - 1, NGRID - 1) * step;

    if (threadIdx.x == 0) scnt = 0;
    __syncthreads();

    for (int h = (int)threadIdx.x; h < nh; h += 256) {
        float x0 = holes[3 * h + 0];
        float y0 = holes[3 * h + 1];
        float sg = holes[3 * h + 2];
        float inv2s2 = 0.5f / (sg * sg);
        float ddx = fmaxf(0.0f, fmaxf(txlo - x0, x0 - txhi));
        float ddy = fmaxf(0.0f, fmaxf(tylo - y0, y0 - tyhi));
        if ((ddx * ddx + ddy * ddy) * inv2s2 < 34.0f) {
            int idx = atomicAdd(&scnt, 1);
            if (idx < MAXH)
                sh[idx] = make_float4(x0, y0, -inv2s2 * LOG2E, 0.0f);
        }
    }
    __syncthreads();
    const int cnt = min(scnt, MAXH);

    // Thread -> pixel mapping: 64 lanes along cols (coalesced stores),
    // 4 thread-rows; each thread: 8 rows (stride 4) x 2 cols (stride 64).
    const int tx = (int)threadIdx.x & 63;
    const int ty = (int)threadIdx.x >> 6;

    const float T  = Tptr[0];
    const float kc = LOG2E / T;  // sigmoid(v) = 1/(1+exp2(-v*log2e))

    int ii[8], jj[2];
#pragma unroll
    for (int r = 0; r < 8; ++r) ii[r] = i0 + ty + 4 * r;
#pragma unroll
    for (int c = 0; c < 2; ++c) jj[c] = j0 + tx + 64 * c;

    if (cnt == 0) {
        // Uniform far-field value: sigmoid((0 - 0.5)/T).
        float e0 = __builtin_amdgcn_exp2f(0.5f * kc);
        float v0 = __builtin_amdgcn_rcpf(1.0f + e0);
#pragma unroll
        for (int r = 0; r < 8; ++r) {
            if (ii[r] >= NGRID) continue;
            size_t rowbase = (size_t)ii[r] * NGRID;
#pragma unroll
            for (int c = 0; c < 2; ++c) {
                if (jj[c] >= NGRID) continue;
                __builtin_nontemporal_store(v0, &out[rowbase + jj[c]]);
            }
        }
        return;
    }

    float xr[8], yc[2];
#pragma unroll
    for (int r = 0; r < 8; ++r) xr[r] = x_start + (float)ii[r] * step;
#pragma unroll
    for (int c = 0; c < 2; ++c) yc[c] = x_start + (float)jj[c] * step;

    float z[8][2];
#pragma unroll
    for (int r = 0; r < 8; ++r)
#pragma unroll
        for (int c = 0; c < 2; ++c) z[r][c] = 0.0f;

    for (int k = 0; k < cnt; ++k) {
        float4 hh = sh[k];  // broadcast read, conflict-free
        float ey[2], ex[8];
#pragma unroll
        for (int c = 0; c < 2; ++c) {
            float dy = yc[c] - hh.y;
            ey[c] = __builtin_amdgcn_exp2f(dy * dy * hh.z);
        }
#pragma unroll
        for (int r = 0; r < 8; ++r) {
            float dx = xr[r] - hh.x;
            ex[r] = __builtin_amdgcn_exp2f(dx * dx * hh.z);
        }
#pragma unroll
        for (int r = 0; r < 8; ++r)
#pragma unroll
            for (int c = 0; c < 2; ++c)
                z[r][c] = fmaf(ex[r], ey[c], z[r][c]);
    }

#pragma unroll
    for (int r = 0; r < 8; ++r) {
        if (ii[r] >= NGRID) continue;
        size_t rowbase = (size_t)ii[r] * NGRID;
#pragma unroll
        for (int c = 0; c < 2; ++c) {
            if (jj[c] >= NGRID) continue;
            float u = (0.5f - z[r][c]) * kc;  // = -(z-0.5)/T * log2e
            float e = __builtin_amdgcn_exp2f(u);
            __builtin_nontemporal_store(__builtin_amdgcn_rcpf(1.0f + e),
                                        &out[rowbase + jj[c]]);
        }
    }
}

extern "C" void kernel_launch(void* const* d_in, const int* in_sizes, int n_in,
                              void* d_out, int out_size, void* d_ws, size_t ws_size,
                              hipStream_t stream) {
    const float* holes = (const float*)d_in[0];
    const float* Tptr  = (const float*)d_in[1];
    float* out = (float*)d_out;
    int nh = in_sizes[0] / 3;

    dim3 grid((NGRID + TJ - 1) / TJ, (NGRID + TI - 1) / TI);
    permit_kernel<<<grid, dim3(256), 0, stream>>>(holes, nh, Tptr, out);
}

// Round 3
// 81.658 us; speedup vs baseline: 1.1139x; 1.1139x over previous
//
#include <hip/hip_runtime.h>

// permittivity = sigmoid((Z - 0.5)/T), Z = sum of 96 isotropic Gaussians on a
// 4001x4001 grid over [-10,10]^2.
//
// Exact-reduction strategy:
//  1. Per-block hole culling vs tile rect: exponent >= 34 -> contribution
//     < e^-34 ~ 2e-15, invisible vs 2e-2 threshold.
//  2. Separable exp: exp(-(dx^2+dy^2)/2s^2) = ex(dx)*ey(dy): 10 exp2 + 16 FMA
//     per hole per 16-pixel thread tile.
//  3. Block-uniform fast path for empty shortlists (~84% of tiles): store a
//     single precomputed sigmoid(-0.5/T) constant, no transcendentals.
// Regime: write-BW-bound on the 64 MB output (floor ~11 us at 6 TB/s).
//
// R2 post-mortem: __builtin_nontemporal_store regressed headline +9 us —
// nt bypasses L2 write-combining, turning dword stores into partial-line HBM
// writes (RMW). Reverted to normal stores (L2 write-back combines lines).

#define NGRID 4001
#define TI 32      // rows (x-axis) per block
#define TJ 128     // cols (y-axis) per block
#define MAXH 128   // LDS shortlist capacity (only 96 holes exist)

__global__ __launch_bounds__(256) void permit_kernel(
    const float* __restrict__ holes, int nh,
    const float* __restrict__ Tptr,
    float* __restrict__ out)
{
    __shared__ float4 sh[MAXH];
    __shared__ int scnt;

    const float step    = 20.0f / 4000.0f;
    const float x_start = -10.0f;
    const float LOG2E   = 1.4426950408889634f;

    const int i0 = blockIdx.y * TI;  // row (x) origin
    const int j0 = blockIdx.x * TJ;  // col (y) origin

    // Tile rect bounds (block-uniform) for culling.
    const float txlo = x_start + i0 * step;
    const float txhi = x_start + (float)min(i0 + TI - 1, NGRID - 1) * step;
    const float tylo = x_start + j0 * step;
    const float tyhi = x_start + (float)min(j0 + TJ - 1, NGRID - 1) * step;

    if (threadIdx.x == 0) scnt = 0;
    __syncthreads();

    for (int h = (int)threadIdx.x; h < nh; h += 256) {
        float x0 = holes[3 * h + 0];
        float y0 = holes[3 * h + 1];
        float sg = holes[3 * h + 2];
        float inv2s2 = 0.5f / (sg * sg);
        float ddx = fmaxf(0.0f, fmaxf(txlo - x0, x0 - txhi));
        float ddy = fmaxf(0.0f, fmaxf(tylo - y0, y0 - tyhi));
        if ((ddx * ddx + ddy * ddy) * inv2s2 < 34.0f) {
            int idx = atomicAdd(&scnt, 1);
            if (idx < MAXH)
                sh[idx] = make_float4(x0, y0, -inv2s2 * LOG2E, 0.0f);
        }
    }
    __syncthreads();
    const int cnt = min(scnt, MAXH);

    // Thread -> pixel mapping: 64 lanes along cols (coalesced stores),
    // 4 thread-rows; each thread: 8 rows (stride 4) x 2 cols (stride 64).
    const int tx = (int)threadIdx.x & 63;
    const int ty = (int)threadIdx.x >> 6;

    const float T  = Tptr[0];
    const float kc = LOG2E / T;  // sigmoid(v) = 1/(1+exp2(-v*log2e))

    int ii[8], jj[2];
#pragma unroll
    for (int r = 0; r < 8; ++r) ii[r] = i0 + ty + 4 * r;
#pragma unroll
    for (int c = 0; c < 2; ++c) jj[c] = j0 + tx + 64 * c;

    if (cnt == 0) {
        // Uniform far-field value: sigmoid((0 - 0.5)/T).
        float e0 = __builtin_amdgcn_exp2f(0.5f * kc);
        float v0 = __builtin_amdgcn_rcpf(1.0f + e0);
#pragma unroll
        for (int r = 0; r < 8; ++r) {
            if (ii[r] >= NGRID) continue;
            size_t rowbase = (size_t)ii[r] * NGRID;
#pragma unroll
            for (int c = 0; c < 2; ++c) {
                if (jj[c] >= NGRID) continue;
                out[rowbase + jj[c]] = v0;
            }
        }
        return;
    }

    float xr[8], yc[2];
#pragma unroll
    for (int r = 0; r < 8; ++r) xr[r] = x_start + (float)ii[r] * step;
#pragma unroll
    for (int c = 0; c < 2; ++c) yc[c] = x_start + (float)jj[c] * step;

    float z[8][2];
#pragma unroll
    for (int r = 0; r < 8; ++r)
#pragma unroll
        for (int c = 0; c < 2; ++c) z[r][c] = 0.0f;

    for (int k = 0; k < cnt; ++k) {
        float4 hh = sh[k];  // broadcast read, conflict-free
        float ey[2], ex[8];
#pragma unroll
        for (int c = 0; c < 2; ++c) {
            float dy = yc[c] - hh.y;
            ey[c] = __builtin_amdgcn_exp2f(dy * dy * hh.z);
        }
#pragma unroll
        for (int r = 0; r < 8; ++r) {
            float dx = xr[r] - hh.x;
            ex[r] = __builtin_amdgcn_exp2f(dx * dx * hh.z);
        }
#pragma unroll
        for (int r = 0; r < 8; ++r)
#pragma unroll
            for (int c = 0; c < 2; ++c)
                z[r][c] = fmaf(ex[r], ey[c], z[r][c]);
    }

#pragma unroll
    for (int r = 0; r < 8; ++r) {
        if (ii[r] >= NGRID) continue;
        size_t rowbase = (size_t)ii[r] * NGRID;
#pragma unroll
        for (int c = 0; c < 2; ++c) {
            if (jj[c] >= NGRID) continue;
            float u = (0.5f - z[r][c]) * kc;  // = -(z-0.5)/T * log2e
            float e = __builtin_amdgcn_exp2f(u);
            out[rowbase + jj[c]] = __builtin_amdgcn_rcpf(1.0f + e);
        }
    }
}

extern "C" void kernel_launch(void* const* d_in, const int* in_sizes, int n_in,
                              void* d_out, int out_size, void* d_ws, size_t ws_size,
                              hipStream_t stream) {
    const float* holes = (const float*)d_in[0];
    const float* Tptr  = (const float*)d_in[1];
    float* out = (float*)d_out;
    int nh = in_sizes[0] / 3;

    dim3 grid((NGRID + TJ - 1) / TJ, (NGRID + TI - 1) / TI);
    permit_kernel<<<grid, dim3(256), 0, stream>>>(holes, nh, Tptr, out);
}